// Round 10
// baseline (184.907 us; speedup 1.0000x reference)
//
#include <hip/hip_runtime.h>

#define LOG2E 1.4426950408889634f
#define BN_EPS 1e-5f

typedef float f32x2 __attribute__((ext_vector_type(2)));

__device__ __forceinline__ float relu_(float x){ return fmaxf(x, 0.f); }

__device__ __forceinline__ float wsum(float v){
    #pragma unroll
    for (int m = 32; m >= 1; m >>= 1) v += __shfl_xor(v, m, 64);
    return v;
}

__device__ constexpr int TRI(int j, int l){ return j*9 - j*(j-1)/2 + (l - j); }

__device__ __forceinline__ void load_h0(const float* __restrict__ x, const float* __restrict__ emb,
                                        long row, float h0[9])
{
    const float4* xv = (const float4*)(x + row * 8);
    float4 p = xv[0];
    float4 q = xv[1];
    int idx = (int)p.x;
    float2 e = ((const float2*)emb)[idx];
    h0[0] = e.x; h0[1] = e.y;
    h0[2] = p.y; h0[3] = p.z; h0[4] = p.w;
    h0[5] = q.x; h0[6] = q.y; h0[7] = q.z; h0[8] = q.w;
}

// ---------------- Kernel 1: moments of h0 ----------------
__global__ __launch_bounds__(256) void k_moments(const float* __restrict__ x, const float* __restrict__ emb,
                                                 float* __restrict__ stats, int B)
{
    float s9[9], mt[45];
    #pragma unroll
    for (int j = 0; j < 9; ++j) s9[j] = 0.f;
    #pragma unroll
    for (int t = 0; t < 45; ++t) mt[t] = 0.f;

    long base = (long)blockIdx.x * 1024 + threadIdx.x;
    #pragma unroll
    for (int r = 0; r < 4; ++r){
        long row = base + r * 256;
        if (row < B){
            float h0[9];
            load_h0(x, emb, row, h0);
            #pragma unroll
            for (int j = 0; j < 9; ++j){
                s9[j] += h0[j];
                #pragma unroll
                for (int l = j; l < 9; ++l)
                    mt[TRI(j,l)] = fmaf(h0[j], h0[l], mt[TRI(j,l)]);
            }
        }
    }
    __shared__ float sm[54];
    if (threadIdx.x < 54) sm[threadIdx.x] = 0.f;
    __syncthreads();
    bool l0 = (threadIdx.x & 63) == 0;
    #pragma unroll
    for (int j = 0; j < 9; ++j){
        float v = wsum(s9[j]);
        if (l0) atomicAdd(&sm[j], v);
    }
    #pragma unroll
    for (int t = 0; t < 45; ++t){
        float v = wsum(mt[t]);
        if (l0) atomicAdd(&sm[9 + t], v);
    }
    __syncthreads();
    if (threadIdx.x < 9)  atomicAdd(&stats[threadIdx.x], sm[threadIdx.x]);
    else if (threadIdx.x < 54) atomicAdd(&stats[16 + threadIdx.x - 9], sm[threadIdx.x]);
}

// BN1 scale/shift from moments; threads 0..17 -> LDS
__device__ __forceinline__ void bn1_from_moments(const float* __restrict__ stats,
                                                 const float* __restrict__ W1, const float* __restrict__ b1,
                                                 const float* __restrict__ g1, const float* __restrict__ be1,
                                                 float invB, float* smem_sc, float* smem_sh)
{
    if (threadIdx.x < 18){
        int k = threadIdx.x;
        float w[9];
        #pragma unroll
        for (int j = 0; j < 9; ++j) w[j] = W1[k*9 + j];
        float dot9 = 0.f, q = 0.f;
        #pragma unroll
        for (int j = 0; j < 9; ++j){
            dot9 = fmaf(w[j], stats[j], dot9);
            q = fmaf(w[j]*w[j], stats[16 + TRI(j,j)], q);
            #pragma unroll
            for (int l = j+1; l < 9; ++l)
                q = fmaf(2.f*w[j]*w[l], stats[16 + TRI(j,l)], q);
        }
        float m1  = dot9 * invB;
        float var = fmaf(-m1, m1, q * invB);
        float mu  = m1 + b1[k];
        float sc  = g1[k] * __builtin_amdgcn_rsqf(var + BN_EPS);
        smem_sc[k] = sc;
        smem_sh[k] = fmaf(-mu, sc, be1[k]);
    }
    __syncthreads();
}

// ---------------- Kernel 2: z2 stats (+ z2 cache) ----------------
template<int STORE_Z2>
__global__ __launch_bounds__(256) void k_stats2(const float* __restrict__ x, const float* __restrict__ emb,
                                                const float* __restrict__ W1, const float* __restrict__ b1,
                                                const float* __restrict__ g1, const float* __restrict__ be1,
                                                const float* __restrict__ W2, const float* __restrict__ b2,
                                                float* __restrict__ stats, float* __restrict__ z2buf, int B)
{
    __shared__ float s_sc[18], s_sh[18];
    bn1_from_moments(stats, W1, b1, g1, be1, 1.f/(float)B, s_sc, s_sh);

    float sc1[18], sh1[18];
    #pragma unroll
    for (int k = 0; k < 18; ++k){ sc1[k] = s_sc[k]; sh1[k] = s_sh[k]; }

    float as[9], aq[9];
    #pragma unroll
    for (int k = 0; k < 9; ++k){ as[k] = 0.f; aq[k] = 0.f; }

    long base = (long)blockIdx.x * 1024 + threadIdx.x;
    #pragma unroll
    for (int r = 0; r < 4; ++r){
        long row = base + r * 256;
        if (row < B){
            float h0[9];
            load_h0(x, emb, row, h0);
            float a1[18];
            #pragma unroll
            for (int k = 0; k < 18; ++k){
                float s = b1[k];
                #pragma unroll
                for (int j = 0; j < 9; ++j) s = fmaf(W1[k*9 + j], h0[j], s);
                a1[k] = relu_(fmaf(sc1[k], s, sh1[k]));
            }
            #pragma unroll
            for (int k = 0; k < 9; ++k){
                float s = b2[k];
                #pragma unroll
                for (int j = 0; j < 18; ++j) s = fmaf(W2[k*18 + j], a1[j], s);
                as[k] += s; aq[k] = fmaf(s, s, aq[k]);
                if (STORE_Z2) z2buf[(long)k * B + row] = s;
            }
        }
    }
    __shared__ float sm[18];
    if (threadIdx.x < 18) sm[threadIdx.x] = 0.f;
    __syncthreads();
    bool l0 = (threadIdx.x & 63) == 0;
    #pragma unroll
    for (int k = 0; k < 9; ++k){
        float s = wsum(as[k]);
        float q = wsum(aq[k]);
        if (l0){ atomicAdd(&sm[k], s); atomicAdd(&sm[9 + k], q); }
    }
    __syncthreads();
    if (threadIdx.x < 9)       atomicAdd(&stats[64 + threadIdx.x], sm[threadIdx.x]);
    else if (threadIdx.x < 18) atomicAdd(&stats[80 + threadIdx.x - 9], sm[threadIdx.x]);
}

// ---------------- f32x2 helpers (row-pair packing) ----------------
__device__ __forceinline__ f32x2 mk2(float a, float b){ f32x2 r; r.x=a; r.y=b; return r; }
__device__ __forceinline__ f32x2 sp2(float a){ f32x2 r; r.x=a; r.y=a; return r; }
__device__ __forceinline__ f32x2 exp2v(f32x2 v){
    f32x2 r; r.x = __builtin_amdgcn_exp2f(v.x); r.y = __builtin_amdgcn_exp2f(v.y); return r;
}
__device__ __forceinline__ f32x2 rcpv(f32x2 v){
    f32x2 r; r.x = __builtin_amdgcn_rcpf(v.x); r.y = __builtin_amdgcn_rcpf(v.y); return r;
}
__device__ __forceinline__ f32x2 relu2(f32x2 v){
    f32x2 r; r.x = fmaxf(v.x, 0.f); r.y = fmaxf(v.y, 0.f); return r;
}
// fma with scalar (uniform) multiplier
__device__ __forceinline__ f32x2 fmas(float a, f32x2 b, f32x2 c){
    return __builtin_elementwise_fma(sp2(a), b, c);
}

// LSTM cell on a row-pair: raw z's; returns h (f32x2), updates c.
__device__ __forceinline__ f32x2 cellh2(f32x2 zi, f32x2 zf, f32x2 zg, f32x2 zo, f32x2& c){
    f32x2 A  = exp2v(sp2(LOG2E) * zi);
    f32x2 G  = exp2v(sp2(2.f*LOG2E) * zg);
    f32x2 icg = A * (G - sp2(1.f)) * rcpv((sp2(1.f) + A) * (sp2(1.f) + G));   // sig(i)*tanh(g)
    f32x2 Fp = exp2v(sp2(-LOG2E) * zf);
    f32x2 fs = rcpv(sp2(1.f) + Fp);                                            // sig(f)
    c = __builtin_elementwise_fma(fs, c, icg);
    f32x2 O  = exp2v(sp2(LOG2E) * zo);
    f32x2 T  = exp2v(sp2(2.f*LOG2E) * c);
    return O * (T - sp2(1.f)) * rcpv((sp2(1.f) + O) * (sp2(1.f) + T));         // sig(o)*tanh(c)
}

// ---------------- Kernel 3: BN2 + biLSTM x2, TWO rows per thread ----------------
template<int USE_WS>
__global__ __launch_bounds__(256) void k_main2(const float* __restrict__ x, const float* __restrict__ emb,
    const float* __restrict__ W1, const float* __restrict__ b1,
    const float* __restrict__ g1, const float* __restrict__ be1,
    const float* __restrict__ W2, const float* __restrict__ b2,
    const float* __restrict__ g2, const float* __restrict__ be2,
    const float* __restrict__ w1f, const float* __restrict__ u1f, const float* __restrict__ c1f,
    const float* __restrict__ w1r, const float* __restrict__ u1r, const float* __restrict__ c1r,
    const float* __restrict__ w2f, const float* __restrict__ u2f, const float* __restrict__ c2f,
    const float* __restrict__ w2r, const float* __restrict__ u2r, const float* __restrict__ c2r,
    const float* __restrict__ stats, const float* __restrict__ z2buf,
    float* __restrict__ out, int B)
{
    __shared__ float s_sc[18], s_sh[18];
    float invB = 1.f / (float)B;
    if (!USE_WS) bn1_from_moments(stats, W1, b1, g1, be1, invB, s_sc, s_sh);

    long rA = (long)blockIdx.x * 512 + threadIdx.x;
    long rB = rA + 256;
    if (rA >= B) return;
    bool vB = rB < B;
    long rBl = vB ? rB : rA;   // clamp for safe loads

    // ---- a2 = relu(BN2(z2)) for both rows ----
    f32x2 a2[9];
    if (USE_WS){
        #pragma unroll
        for (int k = 0; k < 9; ++k){
            float zA = z2buf[(long)k * B + rA];
            float zBv = z2buf[(long)k * B + rBl];
            a2[k] = mk2(zA, zBv);
        }
    } else {
        float zz[2][9];
        #pragma unroll
        for (int rr = 0; rr < 2; ++rr){
            long row = rr ? rBl : rA;
            float h0[9];
            load_h0(x, emb, row, h0);
            float a1[18];
            #pragma unroll
            for (int k = 0; k < 18; ++k){
                float s = b1[k];
                #pragma unroll
                for (int j = 0; j < 9; ++j) s = fmaf(W1[k*9 + j], h0[j], s);
                a1[k] = relu_(fmaf(s_sc[k], s, s_sh[k]));
            }
            #pragma unroll
            for (int k = 0; k < 9; ++k){
                float s = b2[k];
                #pragma unroll
                for (int j = 0; j < 18; ++j) s = fmaf(W2[k*18 + j], a1[j], s);
                zz[rr][k] = s;
            }
        }
        #pragma unroll
        for (int k = 0; k < 9; ++k) a2[k] = mk2(zz[0][k], zz[1][k]);
    }
    #pragma unroll
    for (int k = 0; k < 9; ++k){
        float mu  = stats[64 + k] * invB;
        float var = fmaf(-mu, mu, stats[80 + k] * invB);
        float sc  = g2[k] * __builtin_amdgcn_rsqf(var + BN_EPS);
        float sh  = fmaf(-mu, sc, be2[k]);
        a2[k] = relu2(fmas(sc, a2[k], sp2(sh)));
    }

    // ---- biLSTM layer 1: 4 chains (2 cells x 2 dirs), each f32x2 over rows ----
    f32x2 hf0 = sp2(0.f), hf1 = sp2(0.f), cf0 = sp2(0.f), cf1 = sp2(0.f);
    f32x2 hr0 = sp2(0.f), hr1 = sp2(0.f), cr0 = sp2(0.f), cr1 = sp2(0.f);
    f32x2 uu[9][4];
    #pragma unroll
    for (int s = 0; s < 9; ++s){
        const int tf = s, tr = 8 - s;
        f32x2 xf = a2[tf], xr = a2[tr];
        // fwd dir
        {
            f32x2 zi0 = fmas(w1f[0], xf, fmas(u1f[0],  hf0, fmas(u1f[1],  hf1, sp2(c1f[0]))));
            f32x2 zi1 = fmas(w1f[1], xf, fmas(u1f[2],  hf0, fmas(u1f[3],  hf1, sp2(c1f[1]))));
            f32x2 zf0 = fmas(w1f[2], xf, fmas(u1f[4],  hf0, fmas(u1f[5],  hf1, sp2(c1f[2]))));
            f32x2 zf1 = fmas(w1f[3], xf, fmas(u1f[6],  hf0, fmas(u1f[7],  hf1, sp2(c1f[3]))));
            f32x2 zg0 = fmas(w1f[4], xf, fmas(u1f[8],  hf0, fmas(u1f[9],  hf1, sp2(c1f[4]))));
            f32x2 zg1 = fmas(w1f[5], xf, fmas(u1f[10], hf0, fmas(u1f[11], hf1, sp2(c1f[5]))));
            f32x2 zo0 = fmas(w1f[6], xf, fmas(u1f[12], hf0, fmas(u1f[13], hf1, sp2(c1f[6]))));
            f32x2 zo1 = fmas(w1f[7], xf, fmas(u1f[14], hf0, fmas(u1f[15], hf1, sp2(c1f[7]))));
            hf0 = cellh2(zi0, zf0, zg0, zo0, cf0);
            hf1 = cellh2(zi1, zf1, zg1, zo1, cf1);
        }
        // rev dir
        {
            f32x2 zi0 = fmas(w1r[0], xr, fmas(u1r[0],  hr0, fmas(u1r[1],  hr1, sp2(c1r[0]))));
            f32x2 zi1 = fmas(w1r[1], xr, fmas(u1r[2],  hr0, fmas(u1r[3],  hr1, sp2(c1r[1]))));
            f32x2 zf0 = fmas(w1r[2], xr, fmas(u1r[4],  hr0, fmas(u1r[5],  hr1, sp2(c1r[2]))));
            f32x2 zf1 = fmas(w1r[3], xr, fmas(u1r[6],  hr0, fmas(u1r[7],  hr1, sp2(c1r[3]))));
            f32x2 zg0 = fmas(w1r[4], xr, fmas(u1r[8],  hr0, fmas(u1r[9],  hr1, sp2(c1r[4]))));
            f32x2 zg1 = fmas(w1r[5], xr, fmas(u1r[10], hr0, fmas(u1r[11], hr1, sp2(c1r[5]))));
            f32x2 zo0 = fmas(w1r[6], xr, fmas(u1r[12], hr0, fmas(u1r[13], hr1, sp2(c1r[6]))));
            f32x2 zo1 = fmas(w1r[7], xr, fmas(u1r[14], hr0, fmas(u1r[15], hr1, sp2(c1r[7]))));
            hr0 = cellh2(zi0, zf0, zg0, zo0, cr0);
            hr1 = cellh2(zi1, zf1, zg1, zo1, cr1);
        }
        uu[tf][0] = relu2(hf0);
        uu[tf][1] = relu2(hf1);
        uu[tr][2] = relu2(hr0);
        uu[tr][3] = relu2(hr1);
    }

    // ---- biLSTM layer 2: 2 chains (fwd, rev), each f32x2 over rows ----
    f32x2 H2f = sp2(0.f), C2fs = sp2(0.f), H2r = sp2(0.f), C2rs = sp2(0.f);
    long oA = rA * 18, oB = rB * 18;
    #pragma unroll
    for (int s = 0; s < 9; ++s){
        const int tf = s, tr = 8 - s;
        // fwd
        {
            f32x2 zi = fmas(w2f[0],  uu[tf][0], fmas(w2f[1],  uu[tf][1], fmas(w2f[2],  uu[tf][2], fmas(w2f[3],  uu[tf][3], fmas(u2f[0], H2f, sp2(c2f[0]))))));
            f32x2 zf = fmas(w2f[4],  uu[tf][0], fmas(w2f[5],  uu[tf][1], fmas(w2f[6],  uu[tf][2], fmas(w2f[7],  uu[tf][3], fmas(u2f[1], H2f, sp2(c2f[1]))))));
            f32x2 zg = fmas(w2f[8],  uu[tf][0], fmas(w2f[9],  uu[tf][1], fmas(w2f[10], uu[tf][2], fmas(w2f[11], uu[tf][3], fmas(u2f[2], H2f, sp2(c2f[2]))))));
            f32x2 zo = fmas(w2f[12], uu[tf][0], fmas(w2f[13], uu[tf][1], fmas(w2f[14], uu[tf][2], fmas(w2f[15], uu[tf][3], fmas(u2f[3], H2f, sp2(c2f[3]))))));
            H2f = cellh2(zi, zf, zg, zo, C2fs);
            out[oA + 2*tf] = H2f.x;
            if (vB) out[oB + 2*tf] = H2f.y;
        }
        // rev
        {
            f32x2 zi = fmas(w2r[0],  uu[tr][0], fmas(w2r[1],  uu[tr][1], fmas(w2r[2],  uu[tr][2], fmas(w2r[3],  uu[tr][3], fmas(u2r[0], H2r, sp2(c2r[0]))))));
            f32x2 zf = fmas(w2r[4],  uu[tr][0], fmas(w2r[5],  uu[tr][1], fmas(w2r[6],  uu[tr][2], fmas(w2r[7],  uu[tr][3], fmas(u2r[1], H2r, sp2(c2r[1]))))));
            f32x2 zg = fmas(w2r[8],  uu[tr][0], fmas(w2r[9],  uu[tr][1], fmas(w2r[10], uu[tr][2], fmas(w2r[11], uu[tr][3], fmas(u2r[2], H2r, sp2(c2r[2]))))));
            f32x2 zo = fmas(w2r[12], uu[tr][0], fmas(w2r[13], uu[tr][1], fmas(w2r[14], uu[tr][2], fmas(w2r[15], uu[tr][3], fmas(u2r[3], H2r, sp2(c2r[3]))))));
            H2r = cellh2(zi, zf, zg, zo, C2rs);
            out[oA + 2*tr + 1] = H2r.x;
            if (vB) out[oB + 2*tr + 1] = H2r.y;
        }
    }
}

extern "C" void kernel_launch(void* const* d_in, const int* in_sizes, int n_in,
                              void* d_out, int out_size, void* d_ws, size_t ws_size,
                              hipStream_t stream)
{
    const float* x    = (const float*)d_in[0];
    const float* emb  = (const float*)d_in[1];
    const float* W1   = (const float*)d_in[2];
    const float* b1   = (const float*)d_in[3];
    const float* g1   = (const float*)d_in[4];
    const float* be1  = (const float*)d_in[5];
    const float* W2   = (const float*)d_in[6];
    const float* b2   = (const float*)d_in[7];
    const float* g2   = (const float*)d_in[8];
    const float* be2  = (const float*)d_in[9];
    const float* l1Wf = (const float*)d_in[10];
    const float* l1Uf = (const float*)d_in[11];
    const float* l1bf = (const float*)d_in[12];
    const float* l1Wr = (const float*)d_in[13];
    const float* l1Ur = (const float*)d_in[14];
    const float* l1br = (const float*)d_in[15];
    const float* l2Wf = (const float*)d_in[16];
    const float* l2Uf = (const float*)d_in[17];
    const float* l2bf = (const float*)d_in[18];
    const float* l2Wr = (const float*)d_in[19];
    const float* l2Ur = (const float*)d_in[20];
    const float* l2br = (const float*)d_in[21];

    int B = in_sizes[0] / 8;
    float* stats = (float*)d_ws;
    float* z2buf = (float*)d_ws + 1024;
    size_t need = (1024 + (size_t)9 * B) * sizeof(float);
    bool use_ws = ws_size >= need;

    // stats: [0:9] sum h0, [16:61] tri moments, [64:73] sum z2, [80:89] sumsq z2
    hipMemsetAsync(d_ws, 0, 128 * sizeof(float), stream);

    int nb12 = (B + 1023) / 1024;
    int nb3  = (B + 511) / 512;   // 2 rows/thread

    k_moments<<<nb12, 256, 0, stream>>>(x, emb, stats, B);
    if (use_ws){
        k_stats2<1><<<nb12, 256, 0, stream>>>(x, emb, W1, b1, g1, be1, W2, b2, stats, z2buf, B);
        k_main2<1><<<nb3, 256, 0, stream>>>(x, emb, W1, b1, g1, be1, W2, b2, g2, be2,
                                            l1Wf, l1Uf, l1bf, l1Wr, l1Ur, l1br,
                                            l2Wf, l2Uf, l2bf, l2Wr, l2Ur, l2br,
                                            stats, z2buf, (float*)d_out, B);
    } else {
        k_stats2<0><<<nb12, 256, 0, stream>>>(x, emb, W1, b1, g1, be1, W2, b2, stats, z2buf, B);
        k_main2<0><<<nb3, 256, 0, stream>>>(x, emb, W1, b1, g1, be1, W2, b2, g2, be2,
                                            l1Wf, l1Uf, l1bf, l1Wr, l1Ur, l1br,
                                            l2Wf, l2Uf, l2bf, l2Wr, l2Ur, l2br,
                                            stats, z2buf, (float*)d_out, B);
    }
}